// Round 9
// baseline (1853.660 us; speedup 1.0000x reference)
//
#include <hip/hip_runtime.h>

#define N_TOK 8192
#define C_DIM 2048
#define F_DIM 5632
#define E_NUM 8
#define BK 64

#define BM 256
#define MAXT 72                      // sum ceil(cnt_e/256) <= 16384/256 + 8 = 72
#define BN1 128
#define GRID1 (MAXT * (F_DIM/BN1))   // 3168, /8 = 396
#define BN2 256
#define KSPLIT 2
#define GRID2 (MAXT * (C_DIM/BN2) * KSPLIT)  // 1152
#define NT1 (C_DIM/BK)               // 32
#define NT2H (F_DIM/BK/KSPLIT)       // 44
#define KHALF (F_DIM/KSPLIT)         // 2816

#define PRE_R 2048
#define PRE_Y 4096
#define PRE_T 45056                  // W1/W3 tcvt: 16 slabs * 2816
#define GRID_PRE (PRE_R + PRE_Y + PRE_T)

typedef __attribute__((ext_vector_type(8))) short bf16x8;
typedef __attribute__((ext_vector_type(4))) float f32x4;

typedef const void __attribute__((address_space(1)))* gas1;
typedef void __attribute__((address_space(3)))* las3;

__device__ __forceinline__ unsigned short f2bf(float f){
  union { float f; unsigned u; } v; v.f = f;
  unsigned r = v.u + 0x7FFFu + ((v.u >> 16) & 1u);   // RNE
  return (unsigned short)(r >> 16);
}

__device__ __forceinline__ void glds16(const unsigned short* g, unsigned short* l){
  __builtin_amdgcn_global_load_lds((gas1)g, (las3)l, 16, 0, 0);
}

#define MFMA_BF16 __builtin_amdgcn_mfma_f32_16x16x32_bf16

// β1: cross-buffer loads landed; β2: kt boundary (drain own ds_reads first)
#define BAR1_VM(N) do{ asm volatile("s_waitcnt vmcnt(" #N ")" ::: "memory"); \
    __builtin_amdgcn_sched_barrier(0); __builtin_amdgcn_s_barrier(); \
    __builtin_amdgcn_sched_barrier(0); } while(0)
#define BAR2() do{ asm volatile("s_waitcnt lgkmcnt(0)" ::: "memory"); \
    __builtin_amdgcn_sched_barrier(0); __builtin_amdgcn_s_barrier(); \
    __builtin_amdgcn_sched_barrier(0); } while(0)

// ---------- fused pre-pass: router(+x cvt) | y-zero | W1/W3 transpose-convert ----------
__global__ __launch_bounds__(256) void k_pre(
    const float* __restrict__ x, const float* __restrict__ Wg,
    const float* __restrict__ W1, const float* __restrict__ W3,
    int* __restrict__ cnt, int* __restrict__ list, float* __restrict__ p_slot,
    unsigned short* __restrict__ xb, unsigned short* __restrict__ wb13,
    float* __restrict__ y)
{
  __shared__ float t[64][65];
  int bid = blockIdx.x;
  int tid = threadIdx.x;

  if (bid < PRE_R){
    int wid = tid >> 6, lane = tid & 63;
    int n = bid * 4 + wid;
    int e = lane >> 3, sub = lane & 7;
    const float* xr = x + (size_t)n * C_DIM;
    float acc = 0.f;
    for (int i0 = sub*4; i0 < C_DIM; i0 += 32){
      float4 v = *(const float4*)&xr[i0];
      acc += v.x * Wg[(i0  )*E_NUM + e];
      acc += v.y * Wg[(i0+1)*E_NUM + e];
      acc += v.z * Wg[(i0+2)*E_NUM + e];
      acc += v.w * Wg[(i0+3)*E_NUM + e];
    }
    acc += __shfl_xor(acc, 1);
    acc += __shfl_xor(acc, 2);
    acc += __shfl_xor(acc, 4);
    float lg[E_NUM];
    #pragma unroll
    for (int j = 0; j < E_NUM; ++j) lg[j] = __shfl(acc, j*8);
    unsigned short* xbr = xb + (size_t)n * C_DIM;
    #pragma unroll
    for (int i0 = lane*4; i0 < C_DIM; i0 += 256){
      float4 v = *(const float4*)&xr[i0];
      ushort4 u; u.x = f2bf(v.x); u.y = f2bf(v.y); u.z = f2bf(v.z); u.w = f2bf(v.w);
      *(ushort4*)&xbr[i0] = u;
    }
    if (lane == 0){
      int e1 = 0; float m1 = lg[0];
      #pragma unroll
      for (int j = 1; j < E_NUM; ++j) if (lg[j] > m1){ m1 = lg[j]; e1 = j; }
      int e2 = -1; float m2 = -1e30f;
      #pragma unroll
      for (int j = 0; j < E_NUM; ++j) if (j != e1 && lg[j] > m2){ m2 = lg[j]; e2 = j; }
      float p1 = 1.f / (1.f + __expf(m2 - m1));
      float p2 = 1.f - p1;
      int pos1 = atomicAdd(&cnt[e1], 1);
      list[e1*N_TOK + pos1] = n*2;
      p_slot[n*2] = p1;
      int pos2 = atomicAdd(&cnt[e2], 1);
      list[e2*N_TOK + pos2] = n*2 + 1;
      p_slot[n*2 + 1] = p2;
    }
    return;
  }
  if (bid < PRE_R + PRE_Y){
    float4* y4 = (float4*)y;
    size_t base = (size_t)(bid - PRE_R) * 1024 + tid;
    float4 z4 = {0.f, 0.f, 0.f, 0.f};
    #pragma unroll
    for (int j = 0; j < 4; ++j) y4[base + j*256] = z4;
    return;
  }
  int rel = bid - (PRE_R + PRE_Y);
  int z = rel / 2816;                  // 0..15 (z<8: W1, z>=8: W3)
  int r2 = rel - z*2816;
  int fx = r2 % 88, cy = r2 / 88;
  const float* in = ((z < 8) ? W1 : W3) + (size_t)(z & 7) * C_DIM * F_DIM;
  unsigned short* out = wb13 + (size_t)z * C_DIM * F_DIM;
  int c0 = fx*64, r0 = cy*64;
  int tx = tid & 63, ty = tid >> 6;    // 64 x 4
  #pragma unroll
  for (int i = 0; i < 16; ++i){
    int r = ty + i*4;
    t[r][tx] = in[(size_t)(r0 + r) * F_DIM + c0 + tx];
  }
  __syncthreads();
  #pragma unroll
  for (int i = 0; i < 16; ++i){
    int cr = ty + i*4;
    out[(size_t)(c0 + cr) * C_DIM + r0 + tx] = f2bf(t[tx][cr]);
  }
}

// ---------------- W2 transpose-convert: [F][C] fp32 -> [C][F] bf16 ----------------
__global__ void k_tw2(const float* __restrict__ W2, unsigned short* __restrict__ wb2){
  __shared__ float t[64][65];
  const float* in = W2 + (size_t)blockIdx.z * F_DIM * C_DIM;
  unsigned short* out = wb2 + (size_t)blockIdx.z * C_DIM * F_DIM;
  int c0 = blockIdx.x * 64, r0 = blockIdx.y * 64;
  int tx = threadIdx.x, ty = threadIdx.y;           // 64 x 4
  #pragma unroll
  for (int i = 0; i < 16; ++i){
    int r = ty + i*4;
    t[r][tx] = in[(size_t)(r0 + r) * C_DIM + c0 + tx];
  }
  __syncthreads();
  #pragma unroll
  for (int i = 0; i < 16; ++i){
    int cr = ty + i*4;
    out[(size_t)(c0 + cr) * F_DIM + r0 + tx] = f2bf(t[tx][cr]);
  }
}

// ---------------- prefix / tile table ----------------
__global__ void k_prefix(const int* __restrict__ cnt, int* __restrict__ meta){
  if (threadIdx.x == 0 && blockIdx.x == 0){
    int acc = 0, t = 0;
    for (int e = 0; e < E_NUM; ++e){
      meta[e] = acc; acc += cnt[e];
      int nt = (cnt[e] + BM - 1) / BM;
      for (int i = 0; i < nt; ++i) meta[16 + t++] = (e << 16) | i;
    }
    meta[8] = t;
  }
}

// ------- GEMM1: 256x128 dual-B, 2-barrier/kt, A-dbuf + B-TRIPLE-buffer (160K LDS) -------
// LDS map (ushort elems): A: (kt&1)*16384 + u*4096   (u=0..3, 2 bufs)
//                         B1: 32768 + slot*8192 + u*4096 (u=0..1, 3 slots)
//                         B3: 57344 + slot*8192 + u*4096
__global__ __launch_bounds__(512, 2) void k_gemm1(
    const unsigned short* __restrict__ xb,
    const unsigned short* __restrict__ wb1,   // [E][F][C] bf16
    const unsigned short* __restrict__ wb3,
    unsigned short* __restrict__ h,
    const int* __restrict__ cnt,
    const int* __restrict__ meta,
    const int* __restrict__ list)
{
  __shared__ __align__(16) unsigned short lds[81920];   // 160 KB
  int o = blockIdx.x;
  int tid = threadIdx.x;

  int w = (o & 7) * (GRID1/8) + (o >> 3);
  int t = w % MAXT;
  int n0 = (w / MAXT) * BN1;
  if (t >= meta[8]) return;
  int info = meta[16 + t];
  int e  = info >> 16;
  int m0 = (info & 0xffff) * BM;
  int count = cnt[e];
  int hbase = meta[e];

  int lane = tid & 63, wid = tid >> 6;
  int wm = wid >> 1, wn = wid & 1;
  int l15 = lane & 15;
  int xc0 = (lane >> 4) ^ (lane & 7);
  int xc1 = xc0 ^ 4;

  int srow = tid >> 3;
  int swz = ((tid & 7) ^ (srow & 7)) * 8;
  const unsigned short* aP[4];
  #pragma unroll
  for (int u = 0; u < 4; ++u){
    int ts = list[e*N_TOK + m0 + u*64 + srow];
    int tok = (ts >> 1) & (N_TOK - 1);
    aP[u] = xb + (size_t)tok * C_DIM + swz;
  }
  const unsigned short* b1P[2];
  const unsigned short* b3P[2];
  #pragma unroll
  for (int u = 0; u < 2; ++u){
    b1P[u] = wb1 + ((size_t)e*F_DIM + n0 + u*64 + srow) * C_DIM + swz;
    b3P[u] = wb3 + ((size_t)e*F_DIM + n0 + u*64 + srow) * C_DIM + swz;
  }
  int ldw = wid * 512;

  #define ST_A(u, kt)      glds16(aP[u]  + (kt)*BK, &lds[((kt)&1)*16384 + (u)*4096 + ldw])
  #define ST_B(u, kt, sl)  do{ \
      glds16(b1P[u] + (kt)*BK, &lds[32768 + (sl)*8192 + (u)*4096 + ldw]); \
      glds16(b3P[u] + (kt)*BK, &lds[57344 + (sl)*8192 + (u)*4096 + ldw]); }while(0)
  #define READ_A(d, ab) do{ _Pragma("unroll") for (int m_ = 0; m_ < 4; ++m_){ \
      int row_ = wm*64 + m_*16 + l15; \
      d[m_][0] = *(const bf16x8*)&lds[(ab) + row_*64 + xc0*8]; \
      d[m_][1] = *(const bf16x8*)&lds[(ab) + row_*64 + xc1*8]; } }while(0)
  #define READ_B(d1, d3, sl, q) do{ int brow_ = wn*64 + (q)*16 + l15; \
      d1[0] = *(const bf16x8*)&lds[32768 + (sl)*8192 + brow_*64 + xc0*8]; \
      d1[1] = *(const bf16x8*)&lds[32768 + (sl)*8192 + brow_*64 + xc1*8]; \
      d3[0] = *(const bf16x8*)&lds[57344 + (sl)*8192 + brow_*64 + xc0*8]; \
      d3[1] = *(const bf16x8*)&lds[57344 + (sl)*8192 + brow_*64 + xc1*8]; }while(0)
  #define MFMA16(q, b1, b3) do{ _Pragma("unroll") for (int m_ = 0; m_ < 4; ++m_){ \
      acc1[m_][q] = MFMA_BF16(a[m_][0], b1[0], acc1[m_][q], 0, 0, 0); \
      acc1[m_][q] = MFMA_BF16(a[m_][1], b1[1], acc1[m_][q], 0, 0, 0); \
      acc3[m_][q] = MFMA_BF16(a[m_][0], b3[0], acc3[m_][q], 0, 0, 0); \
      acc3[m_][q] = MFMA_BF16(a[m_][1], b3[1], acc3[m_][q], 0, 0, 0); } }while(0)

  // prologue: A(0), B(0)->slot0, A(1), B(1)->slot1  (16 issues); retire first 8 = A(0),B(0)
  ST_A(0,0); ST_A(1,0); ST_A(2,0); ST_A(3,0);
  ST_B(0,0,0); ST_B(1,0,0);
  ST_A(0,1); ST_A(1,1); ST_A(2,1); ST_A(3,1);
  ST_B(0,1,1); ST_B(1,1,1);
  asm volatile("s_waitcnt vmcnt(8)" ::: "memory");
  __builtin_amdgcn_sched_barrier(0);
  __builtin_amdgcn_s_barrier();
  __builtin_amdgcn_sched_barrier(0);

  f32x4 zero = {0.f, 0.f, 0.f, 0.f};
  f32x4 acc1[4][4], acc3[4][4];
  #pragma unroll
  for (int m = 0; m < 4; ++m)
    #pragma unroll
    for (int q = 0; q < 4; ++q){ acc1[m][q] = zero; acc3[m][q] = zero; }

  // initial fragments for kt=0
  bf16x8 a[4][2];
  READ_A(a, 0);
  bf16x8 bX1[2], bX3[2], bY1[2], bY3[2];
  READ_B(bX1, bX3, 0, 0);

  int s0 = 0, s1 = 1, s2 = 2;          // B slots for kt, kt+1, kt+2
  for (int kt = 0; kt < NT1; ++kt){
    int abn = ((kt+1)&1)*16384;
    // ---- flow region: stage B(kt+2)->s2, pipelined reads, MFMA q0..q2 ----
    ST_B(0, kt+2, s2); ST_B(1, kt+2, s2);
    READ_B(bY1, bY3, s0, 1);
    __builtin_amdgcn_s_setprio(1);
    MFMA16(0, bX1, bX3);
    __builtin_amdgcn_s_setprio(0);
    ST_A(0, kt+2); ST_A(1, kt+2);
    READ_B(bX1, bX3, s0, 2);
    __builtin_amdgcn_s_setprio(1);
    MFMA16(1, bY1, bY3);
    __builtin_amdgcn_s_setprio(0);
    ST_A(2, kt+2); ST_A(3, kt+2);
    READ_B(bY1, bY3, s0, 3);
    __builtin_amdgcn_s_setprio(1);
    MFMA16(2, bX1, bX3);
    __builtin_amdgcn_s_setprio(0);
    // ---- β1: A(kt+1),B(kt+1) landed for all waves (retire oldest 8 of 16) ----
    BAR1_VM(8);
    bf16x8 an[4][2];
    READ_A(an, abn);
    READ_B(bX1, bX3, s1, 0);
    __builtin_amdgcn_s_setprio(1);
    MFMA16(3, bY1, bY3);
    __builtin_amdgcn_s_setprio(0);
    // ---- β2: kt boundary ----
    BAR2();
    #pragma unroll
    for (int m = 0; m < 4; ++m){ a[m][0] = an[m][0]; a[m][1] = an[m][1]; }
    int tmp = s0; s0 = s1; s1 = s2; s2 = tmp;
  }
  asm volatile("s_waitcnt vmcnt(0)" ::: "memory");

  #pragma unroll
  for (int m = 0; m < 4; ++m){
    #pragma unroll
    for (int r = 0; r < 4; ++r){
      int rloc = m0 + wm*64 + m*16 + ((lane >> 4) * 4) + r;
      if (rloc < count){
        unsigned short* hrow = h + (size_t)(hbase + rloc) * F_DIM + n0 + wn*64 + l15;
        #pragma unroll
        for (int q = 0; q < 4; ++q){
          float v1 = acc1[m][q][r];
          float v3 = acc3[m][q][r];
          float hv = (v1 / (1.f + __expf(-v1))) * v3;
          hrow[q*16] = f2bf(hv);
        }
      }
    }
  }
  #undef ST_A
  #undef ST_B
  #undef READ_A
  #undef READ_B
  #undef MFMA16
}

// ------- GEMM2: 256x256, K-split x2, 2-barrier/kt relaxed schedule (unchanged) -------
__global__ __launch_bounds__(512, 2) void k_gemm2(
    const unsigned short* __restrict__ h,
    const unsigned short* __restrict__ wb2,
    float* __restrict__ y,
    const int* __restrict__ cnt,
    const int* __restrict__ meta,
    const int* __restrict__ list,
    const float* __restrict__ p_slot)
{
  int o = blockIdx.x;
  int w = (o & 7) * (GRID2/8) + (o >> 3);
  int ks = w / (GRID2/KSPLIT);
  int r2 = w % (GRID2/KSPLIT);
  int t = r2 % MAXT;
  int n0 = (r2 / MAXT) * BN2;
  if (t >= meta[8]) return;
  int info = meta[16 + t];
  int e  = info >> 16;
  int m0 = (info & 0xffff) * BM;
  int count = cnt[e];
  int hbase = meta[e];

  __shared__ __align__(16) unsigned short lds[2*32768];

  int tid = threadIdx.x;
  int lane = tid & 63, wid = tid >> 6;
  int wm = wid >> 1, wn = wid & 1;
  int l15 = lane & 15;
  int xc0 = (lane >> 4) ^ (lane & 7);
  int xc1 = xc0 ^ 4;

  int srow = tid >> 3;
  int swz = ((tid & 7) ^ (srow & 7)) * 8;
  size_t kb0 = (size_t)ks * KHALF;
  const unsigned short* aP[4];
  #pragma unroll
  for (int u = 0; u < 4; ++u)
    aP[u] = h + (size_t)(hbase + m0 + u*64 + srow) * F_DIM + kb0 + swz;
  const unsigned short* bP[4];
  #pragma unroll
  for (int u = 0; u < 4; ++u)
    bP[u] = wb2 + ((size_t)e*C_DIM + n0 + u*64 + srow) * F_DIM + kb0 + swz;
  int ldw = wid * 512;

  #define ST_A2(u, kt) glds16(aP[u] + (kt)*BK, &lds[((kt)&1)*32768 + (u)*4096 + ldw])
  #define ST_B2(u, kt) glds16(bP[u] + (kt)*BK, &lds[((kt)&1)*32768 + 16384 + (u)*4096 + ldw])
  #define READ_A2(d, buf) do{ _Pragma("unroll") for (int m_ = 0; m_ < 4; ++m_){ \
      int row_ = wm*64 + m_*16 + l15; \
      d[m_][0] = *(const bf16x8*)&(buf)[row_*64 + xc0*8]; \
      d[m_][1] = *(const bf16x8*)&(buf)[row_*64 + xc1*8]; } }while(0)
  #define READ_B2(d, buf, q) do{ _Pragma("unroll") for (int j_ = 0; j_ < 2; ++j_){ \
      int brow_ = wn*128 + ((q)*2 + j_)*16 + l15; \
      d[j_][0] = *(const bf16x8*)&(buf)[16384 + brow_*64 + xc0*8]; \
      d[j_][1] = *(const bf16x8*)&(buf)[16384 + brow_*64 + xc1*8]; } }while(0)
  #define MFMA2(qb, d) do{ _Pragma("unroll") for (int m_ = 0; m_ < 4; ++m_) \
      _Pragma("unroll") for (int j_ = 0; j_ < 2; ++j_){ \
        acc[m_][(qb)*2+j_] = MFMA_BF16(a[m_][0], d[j_][0], acc[m_][(qb)*2+j_], 0, 0, 0); \
        acc[m_][(qb)*2+j_] = MFMA_BF16(a[m_][1], d[j_][1], acc[m_][(qb)*2+j_], 0, 0, 0); } }while(0)

  ST_A2(0,0); ST_A2(1,0); ST_A2(2,0); ST_A2(3,0);
  ST_B2(0,0); ST_B2(1,0); ST_B2(2,0); ST_B2(3,0);
  asm volatile("s_waitcnt vmcnt(4)" ::: "memory");
  ST_A2(0,1); ST_A2(1,1); ST_A2(2,1); ST_A2(3,1);
  ST_B2(0,1); ST_B2(2,1);
  asm volatile("s_waitcnt vmcnt(6)" ::: "memory");
  __builtin_amdgcn_sched_barrier(0);
  __builtin_amdgcn_s_barrier();
  __builtin_amdgcn_sched_barrier(0);

  f32x4 zero = {0.f, 0.f, 0.f, 0.f};
  f32x4 acc[4][8];
  #pragma unroll
  for (int m = 0; m < 4; ++m)
    #pragma unroll
    for (int nf = 0; nf < 8; ++nf) acc[m][nf] = zero;

  bf16x8 a[4][2];
  READ_A2(a, lds);
  bf16x8 bfX[2][2], bfY[2][2];
  READ_B2(bfX, lds, 0);

  for (int kt = 0; kt < NT2H; ++kt){
    const unsigned short* bufc = &lds[(kt & 1)*32768];
    const unsigned short* bufn = &lds[((kt+1) & 1)*32768];
    // ---- flow region ----
    ST_B2(1, kt+1); ST_B2(3, kt+1);
    READ_B2(bfY, bufc, 1);
    __builtin_amdgcn_s_setprio(1);
    MFMA2(0, bfX);
    __builtin_amdgcn_s_setprio(0);
    ST_A2(0, kt+2); ST_A2(1, kt+2);
    READ_B2(bfX, bufc, 2);
    __builtin_amdgcn_s_setprio(1);
    MFMA2(1, bfY);
    __builtin_amdgcn_s_setprio(0);
    ST_A2(2, kt+2); ST_A2(3, kt+2);
    READ_B2(bfY, bufc, 3);
    __builtin_amdgcn_s_setprio(1);
    MFMA2(2, bfX);
    __builtin_amdgcn_s_setprio(0);
    // ---- β1 ----
    ST_B2(0, kt+2); ST_B2(2, kt+2);
    BAR1_VM(6);
    bf16x8 an[4][2];
    READ_A2(an, bufn);
    READ_B2(bfX, bufn, 0);
    __builtin_amdgcn_s_setprio(1);
    MFMA2(3, bfY);
    __builtin_amdgcn_s_setprio(0);
    // ---- β2 ----
    BAR2();
    #pragma unroll
    for (int m = 0; m < 4; ++m){ a[m][0] = an[m][0]; a[m][1] = an[m][1]; }
  }
  asm volatile("s_waitcnt vmcnt(0)" ::: "memory");

  #pragma unroll
  for (int m = 0; m < 4; ++m){
    #pragma unroll
    for (int r = 0; r < 4; ++r){
      int rloc = m0 + wm*64 + m*16 + ((lane >> 4) * 4) + r;
      if (rloc < count){
        int ts = list[e*N_TOK + rloc];
        float p = p_slot[ts];
        int tok = ts >> 1;
        float* yr = y + (size_t)tok * C_DIM + n0 + wn*128 + l15;
        #pragma unroll
        for (int nf = 0; nf < 8; ++nf)
          atomicAdd(&yr[nf*16], p * acc[m][nf][r]);
      }
    }
  }
  #undef ST_A2
  #undef ST_B2
  #undef READ_A2
  #undef READ_B2
  #undef MFMA2
}

extern "C" void kernel_launch(void* const* d_in, const int* in_sizes, int n_in,
                              void* d_out, int out_size, void* d_ws, size_t ws_size,
                              hipStream_t stream)
{
  const float* x  = (const float*)d_in[0];
  const float* Wg = (const float*)d_in[1];
  const float* W1 = (const float*)d_in[2];
  const float* W3 = (const float*)d_in[3];
  const float* W2 = (const float*)d_in[4];
  float* y = (float*)d_out;
  (void)in_sizes; (void)n_in; (void)out_size; (void)ws_size;

  char* ws = (char*)d_ws;
  size_t o = 0;
  auto alloc = [&](size_t bytes)->char* {
    char* p = ws + o;
    o = (o + bytes + 255) & ~(size_t)255;
    return p;
  };
  int*    cnt    = (int*)  alloc(E_NUM * 4);
  int*    meta   = (int*)  alloc(160 * 4);
  float*  p_slot = (float*)alloc((size_t)2*N_TOK * 4);
  int*    list   = (int*)  alloc((size_t)E_NUM*N_TOK * 4);
  unsigned short* xb  = (unsigned short*)alloc((size_t)N_TOK*C_DIM * 2 + 65536);
  unsigned short* wb1 = (unsigned short*)alloc((size_t)E_NUM*C_DIM*F_DIM * 2);  // wb13: W1 slabs
  unsigned short* wb3 = (unsigned short*)alloc((size_t)E_NUM*C_DIM*F_DIM * 2);  // then W3 slabs
  unsigned short* wb2 = (unsigned short*)alloc((size_t)E_NUM*C_DIM*F_DIM * 2);
  unsigned short* h   = (unsigned short*)alloc((size_t)(2*N_TOK + 1024)*F_DIM * 2 + 65536); // +guard
  (void)wb3;

  hipMemsetAsync(cnt, 0, E_NUM * 4, stream);
  k_pre<<<GRID_PRE, 256, 0, stream>>>(x, Wg, W1, W3, cnt, list, p_slot, xb, wb1, y);
  k_prefix<<<1, 64, 0, stream>>>(cnt, meta);
  k_tw2<<<dim3(C_DIM/64, F_DIM/64, E_NUM), dim3(64,4), 0, stream>>>(W2, wb2);
  k_gemm1<<<GRID1, 512, 0, stream>>>(xb, wb1, wb3, h, cnt, meta, list);
  k_gemm2<<<GRID2, 512, 0, stream>>>(h, wb2, y, cnt, meta, list, p_slot);
}

// Round 10
// 1697.399 us; speedup vs baseline: 1.0921x; 1.0921x over previous
//
#include <hip/hip_runtime.h>

#define N_TOK 8192
#define C_DIM 2048
#define F_DIM 5632
#define E_NUM 8
#define BK 64

#define BM 256
#define MAXT 72                      // sum ceil(cnt_e/256) <= 16384/256 + 8 = 72
#define BN1 128
#define GRID1 (MAXT * (F_DIM/BN1))   // 3168, /8 = 396
#define BN2 256
#define KSPLIT 2
#define GRID2 (MAXT * (C_DIM/BN2) * KSPLIT)  // 1152
#define NT1 (C_DIM/BK)               // 32
#define NT2H (F_DIM/BK/KSPLIT)       // 44
#define KHALF (F_DIM/KSPLIT)         // 2816

#define PRE_R 2048
#define PRE_T 45056                  // W1/W3 tcvt: 16 slabs * 2816
#define GRID_PRE (PRE_R + PRE_T)

typedef __attribute__((ext_vector_type(8))) short bf16x8;
typedef __attribute__((ext_vector_type(4))) float f32x4;

typedef const void __attribute__((address_space(1)))* gas1;
typedef void __attribute__((address_space(3)))* las3;

__device__ __forceinline__ unsigned short f2bf(float f){
  union { float f; unsigned u; } v; v.f = f;
  unsigned r = v.u + 0x7FFFu + ((v.u >> 16) & 1u);   // RNE
  return (unsigned short)(r >> 16);
}

__device__ __forceinline__ void glds16(const unsigned short* g, unsigned short* l){
  __builtin_amdgcn_global_load_lds((gas1)g, (las3)l, 16, 0, 0);
}

#define MFMA_BF16 __builtin_amdgcn_mfma_f32_16x16x32_bf16

// β1: cross-buffer loads landed; β2: kt boundary (drain own ds_reads first)
#define BAR1_VM(N) do{ asm volatile("s_waitcnt vmcnt(" #N ")" ::: "memory"); \
    __builtin_amdgcn_sched_barrier(0); __builtin_amdgcn_s_barrier(); \
    __builtin_amdgcn_sched_barrier(0); } while(0)
#define BAR2() do{ asm volatile("s_waitcnt lgkmcnt(0)" ::: "memory"); \
    __builtin_amdgcn_sched_barrier(0); __builtin_amdgcn_s_barrier(); \
    __builtin_amdgcn_sched_barrier(0); } while(0)

// ---------- fused pre-pass: router(+x cvt) | W1/W3 transpose-convert ----------
__global__ __launch_bounds__(256) void k_pre(
    const float* __restrict__ x, const float* __restrict__ Wg,
    const float* __restrict__ W1, const float* __restrict__ W3,
    int* __restrict__ cnt, int* __restrict__ list, float* __restrict__ p_slot,
    unsigned short* __restrict__ xb, unsigned short* __restrict__ wb13)
{
  __shared__ float t[64][65];
  int bid = blockIdx.x;
  int tid = threadIdx.x;

  if (bid < PRE_R){
    int wid = tid >> 6, lane = tid & 63;
    int n = bid * 4 + wid;
    int e = lane >> 3, sub = lane & 7;
    const float* xr = x + (size_t)n * C_DIM;
    float acc = 0.f;
    for (int i0 = sub*4; i0 < C_DIM; i0 += 32){
      float4 v = *(const float4*)&xr[i0];
      acc += v.x * Wg[(i0  )*E_NUM + e];
      acc += v.y * Wg[(i0+1)*E_NUM + e];
      acc += v.z * Wg[(i0+2)*E_NUM + e];
      acc += v.w * Wg[(i0+3)*E_NUM + e];
    }
    acc += __shfl_xor(acc, 1);
    acc += __shfl_xor(acc, 2);
    acc += __shfl_xor(acc, 4);
    float lg[E_NUM];
    #pragma unroll
    for (int j = 0; j < E_NUM; ++j) lg[j] = __shfl(acc, j*8);
    unsigned short* xbr = xb + (size_t)n * C_DIM;
    #pragma unroll
    for (int i0 = lane*4; i0 < C_DIM; i0 += 256){
      float4 v = *(const float4*)&xr[i0];
      ushort4 u; u.x = f2bf(v.x); u.y = f2bf(v.y); u.z = f2bf(v.z); u.w = f2bf(v.w);
      *(ushort4*)&xbr[i0] = u;
    }
    if (lane == 0){
      int e1 = 0; float m1 = lg[0];
      #pragma unroll
      for (int j = 1; j < E_NUM; ++j) if (lg[j] > m1){ m1 = lg[j]; e1 = j; }
      int e2 = -1; float m2 = -1e30f;
      #pragma unroll
      for (int j = 0; j < E_NUM; ++j) if (j != e1 && lg[j] > m2){ m2 = lg[j]; e2 = j; }
      float p1 = 1.f / (1.f + __expf(m2 - m1));
      float p2 = 1.f - p1;
      int pos1 = atomicAdd(&cnt[e1], 1);
      list[e1*N_TOK + pos1] = n*2;
      p_slot[n*2] = p1;
      int pos2 = atomicAdd(&cnt[e2], 1);
      list[e2*N_TOK + pos2] = n*2 + 1;
      p_slot[n*2 + 1] = p2;
    }
    return;
  }
  int rel = bid - PRE_R;
  int z = rel / 2816;                  // 0..15 (z<8: W1, z>=8: W3)
  int r2 = rel - z*2816;
  int fx = r2 % 88, cy = r2 / 88;
  const float* in = ((z < 8) ? W1 : W3) + (size_t)(z & 7) * C_DIM * F_DIM;
  unsigned short* out = wb13 + (size_t)z * C_DIM * F_DIM;
  int c0 = fx*64, r0 = cy*64;
  int tx = tid & 63, ty = tid >> 6;    // 64 x 4
  #pragma unroll
  for (int i = 0; i < 16; ++i){
    int r = ty + i*4;
    t[r][tx] = in[(size_t)(r0 + r) * F_DIM + c0 + tx];
  }
  __syncthreads();
  #pragma unroll
  for (int i = 0; i < 16; ++i){
    int cr = ty + i*4;
    out[(size_t)(c0 + cr) * C_DIM + r0 + tx] = f2bf(t[tx][cr]);
  }
}

// ---------------- W2 transpose-convert: [F][C] fp32 -> [C][F] bf16 ----------------
__global__ void k_tw2(const float* __restrict__ W2, unsigned short* __restrict__ wb2){
  __shared__ float t[64][65];
  const float* in = W2 + (size_t)blockIdx.z * F_DIM * C_DIM;
  unsigned short* out = wb2 + (size_t)blockIdx.z * C_DIM * F_DIM;
  int c0 = blockIdx.x * 64, r0 = blockIdx.y * 64;
  int tx = threadIdx.x, ty = threadIdx.y;           // 64 x 4
  #pragma unroll
  for (int i = 0; i < 16; ++i){
    int r = ty + i*4;
    t[r][tx] = in[(size_t)(r0 + r) * C_DIM + c0 + tx];
  }
  __syncthreads();
  #pragma unroll
  for (int i = 0; i < 16; ++i){
    int cr = ty + i*4;
    out[(size_t)(c0 + cr) * F_DIM + r0 + tx] = f2bf(t[tx][cr]);
  }
}

// ---------------- prefix / tile table ----------------
__global__ void k_prefix(const int* __restrict__ cnt, int* __restrict__ meta){
  if (threadIdx.x == 0 && blockIdx.x == 0){
    int acc = 0, t = 0;
    for (int e = 0; e < E_NUM; ++e){
      meta[e] = acc; acc += cnt[e];
      int nt = (cnt[e] + BM - 1) / BM;
      for (int i = 0; i < nt; ++i) meta[16 + t++] = (e << 16) | i;
    }
    meta[8] = t;
  }
}

// ------- GEMM1: 256x128 dual-B, 2-barrier/kt relaxed schedule (round-8 best) -------
__global__ __launch_bounds__(512, 2) void k_gemm1(
    const unsigned short* __restrict__ xb,
    const unsigned short* __restrict__ wb1,   // [E][F][C] bf16
    const unsigned short* __restrict__ wb3,
    unsigned short* __restrict__ h,
    const int* __restrict__ cnt,
    const int* __restrict__ meta,
    const int* __restrict__ list)
{
  __shared__ __align__(16) unsigned short lds[2*32768];
  int o = blockIdx.x;
  int tid = threadIdx.x;

  int w = (o & 7) * (GRID1/8) + (o >> 3);
  int t = w % MAXT;
  int n0 = (w / MAXT) * BN1;
  if (t >= meta[8]) return;
  int info = meta[16 + t];
  int e  = info >> 16;
  int m0 = (info & 0xffff) * BM;
  int count = cnt[e];
  int hbase = meta[e];

  int lane = tid & 63, wid = tid >> 6;
  int wm = wid >> 1, wn = wid & 1;
  int l15 = lane & 15;
  int xc0 = (lane >> 4) ^ (lane & 7);
  int xc1 = xc0 ^ 4;

  int srow = tid >> 3;
  int swz = ((tid & 7) ^ (srow & 7)) * 8;
  const unsigned short* aP[4];
  #pragma unroll
  for (int u = 0; u < 4; ++u){
    int ts = list[e*N_TOK + m0 + u*64 + srow];
    int tok = (ts >> 1) & (N_TOK - 1);
    aP[u] = xb + (size_t)tok * C_DIM + swz;
  }
  const unsigned short* bP[4];
  #pragma unroll
  for (int u = 0; u < 4; ++u){
    const unsigned short* base = (u < 2) ? wb1 : wb3;
    bP[u] = base + ((size_t)e*F_DIM + n0 + (u & 1)*64 + srow) * C_DIM + swz;
  }
  int ldw = wid * 512;

  #define ST_A(u, kt) glds16(aP[u] + (kt)*BK, &lds[((kt)&1)*32768 + (u)*4096 + ldw])
  #define ST_B(u, kt) glds16(bP[u] + (kt)*BK, &lds[((kt)&1)*32768 + 16384 + (u)*4096 + ldw])
  #define READ_A(d, buf) do{ _Pragma("unroll") for (int m_ = 0; m_ < 4; ++m_){ \
      int row_ = wm*64 + m_*16 + l15; \
      d[m_][0] = *(const bf16x8*)&(buf)[row_*64 + xc0*8]; \
      d[m_][1] = *(const bf16x8*)&(buf)[row_*64 + xc1*8]; } }while(0)
  #define READ_B(d1, d3, buf, q) do{ int brow_ = wn*64 + (q)*16 + l15; \
      d1[0] = *(const bf16x8*)&(buf)[16384 + brow_*64 + xc0*8]; \
      d1[1] = *(const bf16x8*)&(buf)[16384 + brow_*64 + xc1*8]; \
      d3[0] = *(const bf16x8*)&(buf)[24576 + brow_*64 + xc0*8]; \
      d3[1] = *(const bf16x8*)&(buf)[24576 + brow_*64 + xc1*8]; }while(0)
  #define MFMA16(q, b1, b3) do{ _Pragma("unroll") for (int m_ = 0; m_ < 4; ++m_){ \
      acc1[m_][q] = MFMA_BF16(a[m_][0], b1[0], acc1[m_][q], 0, 0, 0); \
      acc1[m_][q] = MFMA_BF16(a[m_][1], b1[1], acc1[m_][q], 0, 0, 0); \
      acc3[m_][q] = MFMA_BF16(a[m_][0], b3[0], acc3[m_][q], 0, 0, 0); \
      acc3[m_][q] = MFMA_BF16(a[m_][1], b3[1], acc3[m_][q], 0, 0, 0); } }while(0)

  ST_A(0,0); ST_A(1,0); ST_A(2,0); ST_A(3,0);
  ST_B(0,0); ST_B(1,0); ST_B(2,0); ST_B(3,0);
  ST_A(0,1); ST_A(1,1); ST_A(2,1); ST_A(3,1);
  asm volatile("s_waitcnt vmcnt(4)" ::: "memory");
  __builtin_amdgcn_sched_barrier(0);
  __builtin_amdgcn_s_barrier();
  __builtin_amdgcn_sched_barrier(0);

  f32x4 zero = {0.f, 0.f, 0.f, 0.f};
  f32x4 acc1[4][4], acc3[4][4];
  #pragma unroll
  for (int m = 0; m < 4; ++m)
    #pragma unroll
    for (int q = 0; q < 4; ++q){ acc1[m][q] = zero; acc3[m][q] = zero; }

  // initial fragments for kt=0 (buffer 0 fully landed)
  bf16x8 a[4][2];
  READ_A(a, lds);
  bf16x8 bX1[2], bX3[2], bY1[2], bY3[2];
  READ_B(bX1, bX3, lds, 0);

  for (int kt = 0; kt < NT1; ++kt){
    const unsigned short* bufc = &lds[(kt & 1)*32768];
    const unsigned short* bufn = &lds[((kt+1) & 1)*32768];
    // ---- flow region (no barriers): stage, pipelined reads, MFMA q0..q2 ----
    ST_B(0, kt+1); ST_B(1, kt+1); ST_B(2, kt+1); ST_B(3, kt+1);
    READ_B(bY1, bY3, bufc, 1);
    __builtin_amdgcn_s_setprio(1);
    MFMA16(0, bX1, bX3);
    __builtin_amdgcn_s_setprio(0);
    ST_A(0, kt+2); ST_A(1, kt+2);
    READ_B(bX1, bX3, bufc, 2);
    __builtin_amdgcn_s_setprio(1);
    MFMA16(1, bY1, bY3);
    __builtin_amdgcn_s_setprio(0);
    ST_A(2, kt+2); ST_A(3, kt+2);
    READ_B(bY1, bY3, bufc, 3);
    __builtin_amdgcn_s_setprio(1);
    MFMA16(2, bX1, bX3);
    __builtin_amdgcn_s_setprio(0);
    // ---- β1: A(kt+1),B(kt+1) landed for all waves ----
    BAR1_VM(4);
    bf16x8 an[4][2];
    READ_A(an, bufn);
    READ_B(bX1, bX3, bufn, 0);
    __builtin_amdgcn_s_setprio(1);
    MFMA16(3, bY1, bY3);
    __builtin_amdgcn_s_setprio(0);
    // ---- β2: kt boundary (drain own ds_reads, then sync) ----
    BAR2();
    #pragma unroll
    for (int m = 0; m < 4; ++m){ a[m][0] = an[m][0]; a[m][1] = an[m][1]; }
  }
  asm volatile("s_waitcnt vmcnt(0)" ::: "memory");

  #pragma unroll
  for (int m = 0; m < 4; ++m){
    #pragma unroll
    for (int r = 0; r < 4; ++r){
      int rloc = m0 + wm*64 + m*16 + ((lane >> 4) * 4) + r;
      if (rloc < count){
        unsigned short* hrow = h + (size_t)(hbase + rloc) * F_DIM + n0 + wn*64 + l15;
        #pragma unroll
        for (int q = 0; q < 4; ++q){
          float v1 = acc1[m][q][r];
          float v3 = acc3[m][q][r];
          float hv = (v1 / (1.f + __expf(-v1))) * v3;
          hrow[q*16] = f2bf(hv);
        }
      }
    }
  }
  #undef ST_A
  #undef ST_B
  #undef READ_A
  #undef READ_B
  #undef MFMA16
}

// ------- GEMM2: 256x256, K-split x2, partials -> ybuf bf16 (NO atomics) -------
__global__ __launch_bounds__(512, 2) void k_gemm2(
    const unsigned short* __restrict__ h,
    const unsigned short* __restrict__ wb2,
    unsigned short* __restrict__ ybuf,        // [KSPLIT][2N][C] bf16
    const int* __restrict__ cnt,
    const int* __restrict__ meta,
    const int* __restrict__ list)
{
  int o = blockIdx.x;
  int w = (o & 7) * (GRID2/8) + (o >> 3);
  int ks = w / (GRID2/KSPLIT);
  int r2 = w % (GRID2/KSPLIT);
  int t = r2 % MAXT;
  int n0 = (r2 / MAXT) * BN2;
  if (t >= meta[8]) return;
  int info = meta[16 + t];
  int e  = info >> 16;
  int m0 = (info & 0xffff) * BM;
  int count = cnt[e];
  int hbase = meta[e];

  __shared__ __align__(16) unsigned short lds[2*32768];

  int tid = threadIdx.x;
  int lane = tid & 63, wid = tid >> 6;
  int wm = wid >> 1, wn = wid & 1;
  int l15 = lane & 15;
  int xc0 = (lane >> 4) ^ (lane & 7);
  int xc1 = xc0 ^ 4;

  int srow = tid >> 3;
  int swz = ((tid & 7) ^ (srow & 7)) * 8;
  size_t kb0 = (size_t)ks * KHALF;
  const unsigned short* aP[4];
  #pragma unroll
  for (int u = 0; u < 4; ++u)
    aP[u] = h + (size_t)(hbase + m0 + u*64 + srow) * F_DIM + kb0 + swz;
  const unsigned short* bP[4];
  #pragma unroll
  for (int u = 0; u < 4; ++u)
    bP[u] = wb2 + ((size_t)e*C_DIM + n0 + u*64 + srow) * F_DIM + kb0 + swz;
  int ldw = wid * 512;

  #define ST_A2(u, kt) glds16(aP[u] + (kt)*BK, &lds[((kt)&1)*32768 + (u)*4096 + ldw])
  #define ST_B2(u, kt) glds16(bP[u] + (kt)*BK, &lds[((kt)&1)*32768 + 16384 + (u)*4096 + ldw])
  #define READ_A2(d, buf) do{ _Pragma("unroll") for (int m_ = 0; m_ < 4; ++m_){ \
      int row_ = wm*64 + m_*16 + l15; \
      d[m_][0] = *(const bf16x8*)&(buf)[row_*64 + xc0*8]; \
      d[m_][1] = *(const bf16x8*)&(buf)[row_*64 + xc1*8]; } }while(0)
  #define READ_B2(d, buf, q) do{ _Pragma("unroll") for (int j_ = 0; j_ < 2; ++j_){ \
      int brow_ = wn*128 + ((q)*2 + j_)*16 + l15; \
      d[j_][0] = *(const bf16x8*)&(buf)[16384 + brow_*64 + xc0*8]; \
      d[j_][1] = *(const bf16x8*)&(buf)[16384 + brow_*64 + xc1*8]; } }while(0)
  #define MFMA2(qb, d) do{ _Pragma("unroll") for (int m_ = 0; m_ < 4; ++m_) \
      _Pragma("unroll") for (int j_ = 0; j_ < 2; ++j_){ \
        acc[m_][(qb)*2+j_] = MFMA_BF16(a[m_][0], d[j_][0], acc[m_][(qb)*2+j_], 0, 0, 0); \
        acc[m_][(qb)*2+j_] = MFMA_BF16(a[m_][1], d[j_][1], acc[m_][(qb)*2+j_], 0, 0, 0); } }while(0)

  ST_A2(0,0); ST_A2(1,0); ST_A2(2,0); ST_A2(3,0);
  ST_B2(0,0); ST_B2(1,0); ST_B2(2,0); ST_B2(3,0);
  asm volatile("s_waitcnt vmcnt(4)" ::: "memory");
  ST_A2(0,1); ST_A2(1,1); ST_A2(2,1); ST_A2(3,1);
  ST_B2(0,1); ST_B2(2,1);
  asm volatile("s_waitcnt vmcnt(6)" ::: "memory");
  __builtin_amdgcn_sched_barrier(0);
  __builtin_amdgcn_s_barrier();
  __builtin_amdgcn_sched_barrier(0);

  f32x4 zero = {0.f, 0.f, 0.f, 0.f};
  f32x4 acc[4][8];
  #pragma unroll
  for (int m = 0; m < 4; ++m)
    #pragma unroll
    for (int nf = 0; nf < 8; ++nf) acc[m][nf] = zero;

  bf16x8 a[4][2];
  READ_A2(a, lds);
  bf16x8 bfX[2][2], bfY[2][2];
  READ_B2(bfX, lds, 0);

  for (int kt = 0; kt < NT2H; ++kt){
    const unsigned short* bufc = &lds[(kt & 1)*32768];
    const unsigned short* bufn = &lds[((kt+1) & 1)*32768];
    // ---- flow region ----
    ST_B2(1, kt+1); ST_B2(3, kt+1);
    READ_B2(bfY, bufc, 1);
    __builtin_amdgcn_s_setprio(1);
    MFMA2(0, bfX);
    __builtin_amdgcn_s_setprio(0);
    ST_A2(0, kt+2); ST_A2(1, kt+2);
    READ_B2(bfX, bufc, 2);
    __builtin_amdgcn_s_setprio(1);
    MFMA2(1, bfY);
    __builtin_amdgcn_s_setprio(0);
    ST_A2(2, kt+2); ST_A2(3, kt+2);
    READ_B2(bfY, bufc, 3);
    __builtin_amdgcn_s_setprio(1);
    MFMA2(2, bfX);
    __builtin_amdgcn_s_setprio(0);
    // ---- β1 ----
    ST_B2(0, kt+2); ST_B2(2, kt+2);
    BAR1_VM(6);
    bf16x8 an[4][2];
    READ_A2(an, bufn);
    READ_B2(bfX, bufn, 0);
    __builtin_amdgcn_s_setprio(1);
    MFMA2(3, bfY);
    __builtin_amdgcn_s_setprio(0);
    // ---- β2 ----
    BAR2();
    #pragma unroll
    for (int m = 0; m < 4; ++m){ a[m][0] = an[m][0]; a[m][1] = an[m][1]; }
  }
  asm volatile("s_waitcnt vmcnt(0)" ::: "memory");

  // epilogue: each (ks, slot, col) element written by exactly ONE block -> no atomics
  #pragma unroll
  for (int m = 0; m < 4; ++m){
    #pragma unroll
    for (int r = 0; r < 4; ++r){
      int rloc = m0 + wm*64 + m*16 + ((lane >> 4) * 4) + r;
      if (rloc < count){
        int ts = list[e*N_TOK + rloc];
        unsigned short* yr = ybuf + ((size_t)ks*(2*N_TOK) + ts)*C_DIM + n0 + wn*128 + l15;
        #pragma unroll
        for (int nf = 0; nf < 8; ++nf)
          yr[nf*16] = f2bf(acc[m][nf][r]);
      }
    }
  }
  #undef ST_A2
  #undef ST_B2
  #undef READ_A2
  #undef READ_B2
  #undef MFMA2
}

// ---- combine: y[n] = p1*(yb0[2n]+yb1[2n]) + p2*(yb0[2n+1]+yb1[2n+1]) ----
__global__ __launch_bounds__(256) void k_combine(
    const unsigned short* __restrict__ ybuf,  // [KSPLIT][2N][C] bf16
    const float* __restrict__ p_slot,
    float* __restrict__ y)
{
  const int CW = C_DIM/8;                     // 256 chunks of 8
  int i = blockIdx.x * blockDim.x + threadIdx.x;
  int stride = gridDim.x * blockDim.x;
  const size_t KS_OFF = (size_t)(2*N_TOK) * C_DIM;
  for (; i < N_TOK*CW; i += stride){
    int n = i >> 8;                           // /CW
    int c0 = (i & 255) * 8;
    size_t b1 = (size_t)(2*n)   * C_DIM + c0;
    size_t b2 = (size_t)(2*n+1) * C_DIM + c0;
    ushort4 a0 = *(const ushort4*)&ybuf[b1];
    ushort4 a1 = *(const ushort4*)&ybuf[b1+4];
    ushort4 a2 = *(const ushort4*)&ybuf[KS_OFF + b1];
    ushort4 a3 = *(const ushort4*)&ybuf[KS_OFF + b1+4];
    ushort4 c2 = *(const ushort4*)&ybuf[b2];
    ushort4 c3 = *(const ushort4*)&ybuf[b2+4];
    ushort4 d2 = *(const ushort4*)&ybuf[KS_OFF + b2];
    ushort4 d3 = *(const ushort4*)&ybuf[KS_OFF + b2+4];
    float p1 = p_slot[2*n], p2 = p_slot[2*n+1];
    float out[8];
    #define B2F(u) __builtin_bit_cast(float, (unsigned)(u) << 16)
    out[0] = p1*(B2F(a0.x)+B2F(a2.x)) + p2*(B2F(c2.x)+B2F(d2.x));
    out[1] = p1*(B2F(a0.y)+B2F(a2.y)) + p2*(B2F(c2.y)+B2F(d2.y));
    out[2] = p1*(B2F(a0.z)+B2F(a2.z)) + p2*(B2F(c2.z)+B2F(d2.z));
    out[3] = p1*(B2F(a0.w)+B2F(a2.w)) + p2*(B2F(c2.w)+B2F(d2.w));
    out[4] = p1*(B2F(a1.x)+B2F(a3.x)) + p2*(B2F(c3.x)+B2F(d3.x));
    out[5] = p1*(B2F(a1.y)+B2F(a3.y)) + p2*(B2F(c3.y)+B2F(d3.y));
    out[6] = p1*(B2F(a1.z)+B2F(a3.z)) + p2*(B2F(c3.z)+B2F(d3.z));
    out[7] = p1*(B2F(a1.w)+B2F(a3.w)) + p2*(B2F(c3.w)+B2F(d3.w));
    #undef B2F
    float4* yo = (float4*)&y[(size_t)n * C_DIM + c0];
    yo[0] = *(float4*)&out[0];
    yo[1] = *(float4*)&out[4];
  }
}

extern "C" void kernel_launch(void* const* d_in, const int* in_sizes, int n_in,
                              void* d_out, int out_size, void* d_ws, size_t ws_size,
                              hipStream_t stream)
{
  const float* x  = (const float*)d_in[0];
  const float* Wg = (const float*)d_in[1];
  const float* W1 = (const float*)d_in[2];
  const float* W3 = (const float*)d_in[3];
  const float* W2 = (const float*)d_in[4];
  float* y = (float*)d_out;
  (void)in_sizes; (void)n_in; (void)out_size; (void)ws_size;

  char* ws = (char*)d_ws;
  size_t o = 0;
  auto alloc = [&](size_t bytes)->char* {
    char* p = ws + o;
    o = (o + bytes + 255) & ~(size_t)255;
    return p;
  };
  int*    cnt    = (int*)  alloc(E_NUM * 4);
  int*    meta   = (int*)  alloc(160 * 4);
  float*  p_slot = (float*)alloc((size_t)2*N_TOK * 4);
  int*    list   = (int*)  alloc((size_t)E_NUM*N_TOK * 4);
  unsigned short* xb  = (unsigned short*)alloc((size_t)N_TOK*C_DIM * 2 + 65536);
  unsigned short* wb1 = (unsigned short*)alloc((size_t)E_NUM*C_DIM*F_DIM * 2);  // wb13: W1 slabs
  unsigned short* wb3 = (unsigned short*)alloc((size_t)E_NUM*C_DIM*F_DIM * 2);  // then W3 slabs
  unsigned short* wb2 = (unsigned short*)alloc((size_t)E_NUM*C_DIM*F_DIM * 2);
  unsigned short* h   = (unsigned short*)alloc((size_t)(2*N_TOK + 1024)*F_DIM * 2 + 65536); // +guard
  unsigned short* ybuf= (unsigned short*)alloc((size_t)KSPLIT*2*N_TOK*C_DIM * 2);
  (void)wb3;

  hipMemsetAsync(cnt, 0, E_NUM * 4, stream);
  k_pre<<<GRID_PRE, 256, 0, stream>>>(x, Wg, W1, W3, cnt, list, p_slot, xb, wb1);
  k_prefix<<<1, 64, 0, stream>>>(cnt, meta);
  k_tw2<<<dim3(C_DIM/64, F_DIM/64, E_NUM), dim3(64,4), 0, stream>>>(W2, wb2);
  k_gemm1<<<GRID1, 512, 0, stream>>>(xb, wb1, wb3, h, cnt, meta, list);
  k_gemm2<<<GRID2, 512, 0, stream>>>(h, wb2, ybuf, cnt, meta, list);
  k_combine<<<4096, 256, 0, stream>>>(ybuf, p_slot, y);
}